// Round 2
// baseline (1293.594 us; speedup 1.0000x reference)
//
#include <hip/hip_runtime.h>
#include <math.h>

#define THREADS 256
#define RPB 32

// ---- LDS layout (bytes) ----
#define OFF_W    0
#define SZ_W     (128*68*4)            // 34816: W1 chunks [j=128][c=64] stride 68 / W2 chunks [n=128][k=64] swizzled
#define OFF_T    (SZ_W)                // 34816
#define SZ_T     (32*516*2)            // 33024: tanh values, bf16, stride 516 shorts
#define OFF_H1   (OFF_T + SZ_T)        // 67840
#define SZ_H1    (32*68*4)             // 8704: h1 [32][68]
#define OFF_CI   (OFF_H1 + SZ_H1)      // 76544
#define SZ_CI    (512*4)               // capinv
#define OFF_EPS  (OFF_CI + SZ_CI)      // 78592
#define OFF_EPSC (OFF_EPS + 128)
#define OFF_RS   (OFF_EPSC + 128)
#define SMEM_BYTES (OFF_RS + 128)      // 78976 < 81920 -> 2 blocks/CU

__device__ __forceinline__ float bf2f(unsigned short u) {
    return __uint_as_float(((unsigned)u) << 16);
}
__device__ __forceinline__ unsigned short f2bf(float v) {
    unsigned u = __float_as_uint(v);
    u += 0x7FFFu + ((u >> 16) & 1u);   // RNE
    return (unsigned short)(u >> 16);
}

__global__ __launch_bounds__(THREADS) void fused_rgu(
    const float* __restrict__ x, const float* __restrict__ xcons,
    const float* __restrict__ cap, const float* __restrict__ W1,
    const float* __restrict__ b1, const float* __restrict__ W2,
    const float* __restrict__ b2, float* __restrict__ out)
{
    extern __shared__ __align__(16) char smem[];
    float* s_w           = (float*)(smem + OFF_W);
    unsigned short* s_t  = (unsigned short*)(smem + OFF_T);
    float* s_h1          = (float*)(smem + OFF_H1);
    float* s_ci          = (float*)(smem + OFF_CI);
    float* s_eps         = (float*)(smem + OFF_EPS);
    float* s_epsC        = (float*)(smem + OFF_EPSC);
    float* s_rs          = (float*)(smem + OFF_RS);

    const int t    = threadIdx.x;
    const int lane = t & 63;
    const int wv   = t >> 6;
    const long r0  = (long)blockIdx.x * RPB;

    // ---------------- P0: cap regs, capinv, capsum ----------------
    float4 capA = *(const float4*)(cap + 4*lane);
    float4 capB = *(const float4*)(cap + 256 + 4*lane);
    {
        float c0 = cap[t], c1 = cap[t + 256];
        s_ci[t] = 1.0f / c0; s_ci[t + 256] = 1.0f / c1;
    }
    float capSum;
    {
        float p = capA.x + capA.y + capA.z + capA.w
                + capB.x + capB.y + capB.z + capB.w;
        #pragma unroll
        for (int m = 1; m < 64; m <<= 1) p += __shfl_xor(p, m, 64);
        capSum = p;
    }
    const float invCapSum = 1.0f / capSum;

    // ---------------- P1: epsilon per row (wave wv -> rows wv*8..+7) ----------------
    #pragma unroll
    for (int rr = 0; rr < 8; ++rr) {
        int r = wv * 8 + rr;
        const float* xr = x + (r0 + r) * 512;
        float4 xA = *(const float4*)(xr + 4*lane);
        float4 xB = *(const float4*)(xr + 256 + 4*lane);
        float d = fmaf(xA.x, capA.x, fmaf(xA.y, capA.y,
                  fmaf(xA.z, capA.z, fmaf(xA.w, capA.w,
                  fmaf(xB.x, capB.x, fmaf(xB.y, capB.y,
                  fmaf(xB.z, capB.z, xB.w * capB.w)))))));
        #pragma unroll
        for (int m = 1; m < 64; m <<= 1) d += __shfl_xor(d, m, 64);
        if (lane == 0) {
            float epsC = fmaf(xcons[r0 + r], capSum, -d);  // eps * capSum
            s_epsC[r] = epsC;
            s_eps[r]  = epsC * invCapSum;
        }
    }
    __syncthreads();

    // ---------------- P2a: init h1 with b1 + eps * W1[:,512] ----------------
    for (int e = t; e < 32 * 64; e += THREADS) {
        int r = e >> 6, c = e & 63;
        s_h1[r * 68 + c] = fmaf(s_eps[r], W1[c * 513 + 512], b1[c]);
    }
    __syncthreads();

    // ---------------- P2b: GEMM1  h1[32][64] += x[32][512] * W1^T ----------------
    // t = kg*64 + rg*16 + cg ; tile: 8 rows x 4 cols, k split 4 ways (kg)
    {
        const int kg = t >> 6;
        const int rg = (t >> 4) & 3;
        const int cg = t & 15;
        float acc[8][4];
        #pragma unroll
        for (int i = 0; i < 8; ++i)
            #pragma unroll
            for (int m = 0; m < 4; ++m) acc[i][m] = 0.f;

        for (int it = 0; it < 4; ++it) {
            // stage W1 window: s_w[row][c], row = kgs*32 + jj, gj = kgs*128 + it*32 + jj
            #pragma unroll
            for (int e = 0; e < 32; ++e) {
                int idx = e * 256 + t;
                int c = idx >> 7;            // 0..63
                int row = idx & 127;         // 0..127
                int kgs = row >> 5, jj = row & 31;
                int gj = kgs * 128 + it * 32 + jj;
                s_w[row * 68 + c] = W1[c * 513 + gj];
            }
            __syncthreads();
            const float* xbase = x + r0 * 512 + kg * 128 + it * 32;
            #pragma unroll
            for (int j4 = 0; j4 < 8; ++j4) {
                float wr[4][4];
                #pragma unroll
                for (int dj = 0; dj < 4; ++dj) {
                    float4 w4 = *(const float4*)&s_w[(kg * 32 + j4 * 4 + dj) * 68 + 4 * cg];
                    wr[dj][0] = w4.x; wr[dj][1] = w4.y; wr[dj][2] = w4.z; wr[dj][3] = w4.w;
                }
                #pragma unroll
                for (int i = 0; i < 8; ++i) {
                    int r = rg * 8 + i;
                    float4 xv = *(const float4*)(xbase + r * 512 + j4 * 4);
                    #pragma unroll
                    for (int m = 0; m < 4; ++m) {
                        acc[i][m] = fmaf(xv.x, wr[0][m],
                                    fmaf(xv.y, wr[1][m],
                                    fmaf(xv.z, wr[2][m],
                                    fmaf(xv.w, wr[3][m], acc[i][m]))));
                    }
                }
            }
            __syncthreads();
        }
        // combine k-split partials
        #pragma unroll
        for (int i = 0; i < 8; ++i) {
            int r = rg * 8 + i;
            #pragma unroll
            for (int m = 0; m < 4; ++m)
                atomicAdd(&s_h1[r * 68 + 4 * cg + m], acc[i][m]);
        }
        __syncthreads();
        // relu in place
        for (int e = t; e < 2048; e += THREADS) {
            int r = e >> 6, c = e & 63;
            float v = s_h1[r * 68 + c];
            s_h1[r * 68 + c] = v > 0.f ? v : 0.f;
        }
        __syncthreads();
    }

    // ---------------- P3: GEMM2 + tanh + rowsum ----------------
    // t = rg2*32 + ng ; tile 4 rows x 4 n ; FOUR n-chunks of 128 (512 total)
    const int ng  = t & 31;
    const int rg2 = t >> 5;
    float rsum[4] = {0.f, 0.f, 0.f, 0.f};
    for (int ch = 0; ch < 4; ++ch) {
        const int n0 = ch * 128;
        // stage W2 chunk, XOR-swizzled over kf4
        #pragma unroll
        for (int e = 0; e < 8; ++e) {
            int f = e * 256 + t;             // 0..2047 float4s
            int n = f >> 4, kf4 = f & 15;
            float4 v = *(const float4*)(W2 + (n0 + n) * 64 + kf4 * 4);
            int swz = kf4 ^ ((9 * (n >> 2) + (n & 3)) & 15);
            *(float4*)&s_w[n * 64 + swz * 4] = v;
        }
        __syncthreads();
        float4 b2v = *(const float4*)(b2 + n0 + 4 * ng);
        float za[4][4];
        #pragma unroll
        for (int i = 0; i < 4; ++i) {
            za[i][0] = b2v.x; za[i][1] = b2v.y; za[i][2] = b2v.z; za[i][3] = b2v.w;
        }
        #pragma unroll
        for (int kf4 = 0; kf4 < 16; ++kf4) {
            float hr[4][4];
            #pragma unroll
            for (int i = 0; i < 4; ++i) {
                float4 h = *(const float4*)&s_h1[(rg2 * 4 + i) * 68 + kf4 * 4];
                hr[i][0] = h.x; hr[i][1] = h.y; hr[i][2] = h.z; hr[i][3] = h.w;
            }
            float wr2[4][4];
            #pragma unroll
            for (int m = 0; m < 4; ++m) {
                int nl = 4 * ng + m;
                int swz = kf4 ^ ((9 * ng + m) & 15);
                float4 w = *(const float4*)&s_w[nl * 64 + swz * 4];
                wr2[m][0] = w.x; wr2[m][1] = w.y; wr2[m][2] = w.z; wr2[m][3] = w.w;
            }
            #pragma unroll
            for (int i = 0; i < 4; ++i)
                #pragma unroll
                for (int m = 0; m < 4; ++m)
                    za[i][m] = fmaf(hr[i][0], wr2[m][0],
                               fmaf(hr[i][1], wr2[m][1],
                               fmaf(hr[i][2], wr2[m][2],
                               fmaf(hr[i][3], wr2[m][3], za[i][m]))));
        }
        #pragma unroll
        for (int i = 0; i < 4; ++i) {
            int r = rg2 * 4 + i;
            #pragma unroll
            for (int m = 0; m < 4; ++m) {
                float tv = tanhf(za[i][m]);
                rsum[i] += tv;
                s_t[r * 516 + n0 + 4 * ng + m] = f2bf(tv);
            }
        }
        __syncthreads();
    }
    // reduce rowsums across the 32 ng lanes (stays within wave halves)
    #pragma unroll
    for (int i = 0; i < 4; ++i) {
        float s = rsum[i];
        #pragma unroll
        for (int msk = 1; msk < 32; msk <<= 1) s += __shfl_xor(s, msk, 64);
        rsum[i] = s;
    }
    if (ng == 0) {
        #pragma unroll
        for (int i = 0; i < 4; ++i) {
            int r = rg2 * 4 + i;
            s_rs[r] = s_epsC[r] / rsum[i];   // eps*capSum / S
        }
    }
    __syncthreads();

    // ---------------- P5: out = x + t * (epsC/S) * capinv ----------------
    {
        const int rr  = t >> 7;              // 0..1
        const int col = (t & 127) * 4;       // 0..508
        #pragma unroll 4
        for (int q = 0; q < 16; ++q) {
            int r = q * 2 + rr;
            float rs = s_rs[r];
            float4 xv = *(const float4*)(x + (r0 + r) * 512 + col);
            ushort4 tv4 = *(const ushort4*)&s_t[r * 516 + col];
            float4 ci = *(const float4*)&s_ci[col];
            float4 o;
            o.x = fmaf(bf2f(tv4.x), rs * ci.x, xv.x);
            o.y = fmaf(bf2f(tv4.y), rs * ci.y, xv.y);
            o.z = fmaf(bf2f(tv4.z), rs * ci.z, xv.z);
            o.w = fmaf(bf2f(tv4.w), rs * ci.w, xv.w);
            *(float4*)(out + (r0 + r) * 512 + col) = o;
        }
    }
}

extern "C" void kernel_launch(void* const* d_in, const int* in_sizes, int n_in,
                              void* d_out, int out_size, void* d_ws, size_t ws_size,
                              hipStream_t stream) {
    const float* x     = (const float*)d_in[0];
    const float* xcons = (const float*)d_in[1];
    const float* cap   = (const float*)d_in[2];
    const float* W1    = (const float*)d_in[3];
    const float* b1    = (const float*)d_in[4];
    const float* W2    = (const float*)d_in[5];
    const float* b2    = (const float*)d_in[6];
    float* out         = (float*)d_out;

    (void)in_sizes; (void)n_in; (void)out_size; (void)d_ws; (void)ws_size;

    hipFuncSetAttribute((const void*)fused_rgu,
                        hipFuncAttributeMaxDynamicSharedMemorySize, SMEM_BYTES);
    fused_rgu<<<65536 / RPB, THREADS, SMEM_BYTES, stream>>>(
        x, xcons, cap, W1, b1, W2, b2, out);
}

// Round 3
// 448.368 us; speedup vs baseline: 2.8851x; 2.8851x over previous
//
#include <hip/hip_runtime.h>
#include <hip/hip_fp16.h>
#include <math.h>

#define THREADS 256
#define RPB 32
#define NBLK (65536 / RPB)   // 2048 blocks

// ---- workspace layout (float offsets) ----
// W1 images: 16 chunks, each [jj=0..31][c=0..67] padded to 3072 floats (12288 B)
//   ws1[it*3072 + jj*68 + c] = W1[c*513 + it*32 + jj]   (c<64; pad cols garbage, never read)
// W2 images: 4 chunks, each 8192 floats, pre-XOR-swizzled LDS image
// W1 last column (epsilon weights): 64 floats
#define WS_W1    0
#define WS_W1_CH 3072
#define WS_W2    (16 * WS_W1_CH)          // 49152
#define WS_W2_CH 8192
#define WS_W1L   (WS_W2 + 4 * WS_W2_CH)   // 81920
// total 81984 floats = 327936 bytes of d_ws

// ---- LDS layout (bytes) ----
#define OFF_W    0
#define SZ_W     32768                    // union: W1 dbuf 2x12288 | W2 chunk 32768
#define W1BUF_B  12288
#define OFF_T    (OFF_W + SZ_W)           // 32768
#define SZ_T     (RPB * 516 * 2)          // 33024, f16 tanh values, stride 516 shorts
#define OFF_H1   (OFF_T + SZ_T)           // 65792
#define SZ_H1    (RPB * 68 * 4)           // 8704
#define OFF_CI   (OFF_H1 + SZ_H1)         // 74496
#define SZ_CI    2048
#define OFF_EPS  (OFF_CI + SZ_CI)         // 76544
#define OFF_EPSC (OFF_EPS + 128)
#define OFF_RS   (OFF_EPSC + 128)
#define SMEM_BYTES (OFF_RS + 128)         // 76928 B -> 2 blocks/CU (160 KiB LDS)

__device__ __forceinline__ float fast_tanh(float z) {
    // tanh(z) = 1 - 2/(e^{2z}+1); saturates correctly for |z| large (inf/0 paths)
    float e = __expf(2.0f * z);
    return fmaf(-2.0f, __builtin_amdgcn_rcpf(e + 1.0f), 1.0f);
}

// ---------------- prep: materialize LDS images of weights in ws ----------------
__global__ __launch_bounds__(256) void prep_kernel(
    const float* __restrict__ W1, const float* __restrict__ W2,
    float* __restrict__ ws)
{
    int tid = blockIdx.x * 256 + threadIdx.x;   // 0..32767, grid = 128 blocks
    // W1 chunk images
    {
        int it = tid >> 11;           // /2048 -> 0..15
        int rem = tid & 2047;
        int jj = rem >> 6, c = rem & 63;
        ws[WS_W1 + it * WS_W1_CH + jj * 68 + c] = W1[c * 513 + it * 32 + jj];
    }
    // W2 swizzled chunk images (linear read, swizzled write)
    {
        int j = tid & 3, kf4 = (tid >> 2) & 15, n = (tid >> 6) & 127, ch = tid >> 13;
        int swz = kf4 ^ ((9 * (n >> 2) + (n & 3)) & 15);
        ws[WS_W2 + ch * WS_W2_CH + n * 64 + swz * 4 + j] = W2[tid];
    }
    if (tid < 64) ws[WS_W1L + tid] = W1[tid * 513 + 512];
}

// ---------------- main fused kernel ----------------
__global__ __launch_bounds__(THREADS, 2) void fused_rgu(
    const float* __restrict__ x, const float* __restrict__ xcons,
    const float* __restrict__ cap, const float* __restrict__ b1,
    const float* __restrict__ b2, const float* __restrict__ ws,
    float* __restrict__ out)
{
    extern __shared__ __align__(16) char smem[];
    float*          s_w    = (float*)(smem + OFF_W);
    unsigned short* s_t    = (unsigned short*)(smem + OFF_T);
    float*          s_h1   = (float*)(smem + OFF_H1);
    float*          s_ci   = (float*)(smem + OFF_CI);
    float*          s_eps  = (float*)(smem + OFF_EPS);
    float*          s_epsC = (float*)(smem + OFF_EPSC);
    float*          s_rs   = (float*)(smem + OFF_RS);

    const int t    = threadIdx.x;
    const int lane = t & 63;
    const int wv   = t >> 6;
    const long r0  = (long)blockIdx.x * RPB;

    // stage W1 chunk 0 into buffer 0 early (overlaps the eps phase's global loads)
    {
        const float4* src = (const float4*)(ws + WS_W1);
        float4* dst = (float4*)(smem + OFF_W);
        dst[t] = src[t]; dst[t + 256] = src[t + 256]; dst[t + 512] = src[t + 512];
    }

    // ---- P0: cap regs, capinv, capSum ----
    float4 capA = *(const float4*)(cap + 4 * lane);
    float4 capB = *(const float4*)(cap + 256 + 4 * lane);
    {
        float c0 = cap[t], c1 = cap[t + 256];
        s_ci[t] = 1.0f / c0; s_ci[t + 256] = 1.0f / c1;
    }
    float capSum;
    {
        float p = capA.x + capA.y + capA.z + capA.w
                + capB.x + capB.y + capB.z + capB.w;
        #pragma unroll
        for (int m = 1; m < 64; m <<= 1) p += __shfl_xor(p, m, 64);
        capSum = p;
    }
    const float invCapSum = 1.0f / capSum;

    // ---- P1: epsilon per row (wave wv -> rows wv*8..+7) ----
    #pragma unroll
    for (int rr = 0; rr < 8; ++rr) {
        int r = wv * 8 + rr;
        const float* xr = x + (r0 + r) * 512;
        float4 xA = *(const float4*)(xr + 4 * lane);
        float4 xB = *(const float4*)(xr + 256 + 4 * lane);
        float d = fmaf(xA.x, capA.x, fmaf(xA.y, capA.y,
                  fmaf(xA.z, capA.z, fmaf(xA.w, capA.w,
                  fmaf(xB.x, capB.x, fmaf(xB.y, capB.y,
                  fmaf(xB.z, capB.z, xB.w * capB.w)))))));
        #pragma unroll
        for (int m = 1; m < 64; m <<= 1) d += __shfl_xor(d, m, 64);
        if (lane == 0) {
            float epsC = fmaf(xcons[r0 + r], capSum, -d);   // eps * capSum
            s_epsC[r] = epsC;
            s_eps[r]  = epsC * invCapSum;
        }
    }
    __syncthreads();   // eps visible + W1 chunk 0 staged

    // ---- GEMM1: h1[32][64] = relu(x[32][512] @ W1T + eps*w1last + b1) ----
    // t = rg*16 + cg : rows 2rg..2rg+1, cols 4cg..4cg+3. acc[2][4], no k-split.
    const int rg = t >> 4;
    const int cg = t & 15;
    float acc0[4] = {0.f, 0.f, 0.f, 0.f};
    float acc1[4] = {0.f, 0.f, 0.f, 0.f};
    {
        const float* xg0 = x + (r0 + 2 * rg) * 512;
        const float* xg1 = xg0 + 512;
        for (int it = 0; it < 16; ++it) {
            const int b = it & 1;
            if (it < 15) {   // prefetch next chunk into other buffer (no extra barrier)
                const float4* src = (const float4*)(ws + WS_W1 + (it + 1) * WS_W1_CH);
                float4* dst = (float4*)(smem + OFF_W + (b ^ 1) * W1BUF_B);
                dst[t] = src[t]; dst[t + 256] = src[t + 256]; dst[t + 512] = src[t + 512];
            }
            const float* w = (const float*)(smem + OFF_W + b * W1BUF_B);
            const int k0 = it * 32;
            #pragma unroll
            for (int j4 = 0; j4 < 8; ++j4) {
                float4 xv0 = *(const float4*)(xg0 + k0 + j4 * 4);
                float4 xv1 = *(const float4*)(xg1 + k0 + j4 * 4);
                const float* wb = &w[(j4 * 4) * 68 + 4 * cg];
                float wr[4][4];
                #pragma unroll
                for (int dj = 0; dj < 4; ++dj) {
                    float4 w4 = *(const float4*)(wb + dj * 68);
                    wr[dj][0] = w4.x; wr[dj][1] = w4.y; wr[dj][2] = w4.z; wr[dj][3] = w4.w;
                }
                #pragma unroll
                for (int m = 0; m < 4; ++m) {
                    acc0[m] = fmaf(xv0.x, wr[0][m], fmaf(xv0.y, wr[1][m],
                              fmaf(xv0.z, wr[2][m], fmaf(xv0.w, wr[3][m], acc0[m]))));
                    acc1[m] = fmaf(xv1.x, wr[0][m], fmaf(xv1.y, wr[1][m],
                              fmaf(xv1.z, wr[2][m], fmaf(xv1.w, wr[3][m], acc1[m]))));
                }
            }
            __syncthreads();
        }
        // bias + eps-column + relu in registers, single b128 store per row
        float4 b1v = *(const float4*)(b1 + 4 * cg);
        float4 wl  = *(const float4*)(ws + WS_W1L + 4 * cg);
        #pragma unroll
        for (int i = 0; i < 2; ++i) {
            float e = s_eps[2 * rg + i];
            const float* a = i ? acc1 : acc0;
            float4 h;
            h.x = fmaxf(a[0] + fmaf(e, wl.x, b1v.x), 0.f);
            h.y = fmaxf(a[1] + fmaf(e, wl.y, b1v.y), 0.f);
            h.z = fmaxf(a[2] + fmaf(e, wl.z, b1v.z), 0.f);
            h.w = fmaxf(a[3] + fmaf(e, wl.w, b1v.w), 0.f);
            *(float4*)&s_h1[(2 * rg + i) * 68 + 4 * cg] = h;
        }
    }

    // ---- GEMM2 + tanh + rowsum: z[32][512] = h1 @ W2T + b2 ----
    // t = rg2*32 + ng : rows rg2*4..+3, cols 4ng..4ng+3 per 128-col chunk
    const int ng  = t & 31;
    const int rg2 = t >> 5;
    float rsum[4] = {0.f, 0.f, 0.f, 0.f};
    for (int ch = 0; ch < 4; ++ch) {
        __syncthreads();   // prior users of s_w done (covers h1 stores for ch=0 too)
        {
            const float4* src = (const float4*)(ws + WS_W2 + ch * WS_W2_CH);
            float4* dst = (float4*)(smem + OFF_W);
            #pragma unroll
            for (int e8 = 0; e8 < 8; ++e8) dst[e8 * 256 + t] = src[e8 * 256 + t];
        }
        __syncthreads();
        const int n0 = ch * 128;
        float4 b2v = *(const float4*)(b2 + n0 + 4 * ng);
        float za[4][4];
        #pragma unroll
        for (int i = 0; i < 4; ++i) {
            za[i][0] = b2v.x; za[i][1] = b2v.y; za[i][2] = b2v.z; za[i][3] = b2v.w;
        }
        #pragma unroll
        for (int kf4 = 0; kf4 < 16; ++kf4) {
            float hr[4][4];
            #pragma unroll
            for (int i = 0; i < 4; ++i) {
                float4 h = *(const float4*)&s_h1[(rg2 * 4 + i) * 68 + kf4 * 4];
                hr[i][0] = h.x; hr[i][1] = h.y; hr[i][2] = h.z; hr[i][3] = h.w;
            }
            float wr2[4][4];
            #pragma unroll
            for (int m = 0; m < 4; ++m) {
                int nl = 4 * ng + m;
                int swz = kf4 ^ ((9 * ng + m) & 15);
                float4 w = *(const float4*)&s_w[nl * 64 + swz * 4];
                wr2[m][0] = w.x; wr2[m][1] = w.y; wr2[m][2] = w.z; wr2[m][3] = w.w;
            }
            #pragma unroll
            for (int i = 0; i < 4; ++i)
                #pragma unroll
                for (int m = 0; m < 4; ++m)
                    za[i][m] = fmaf(hr[i][0], wr2[m][0], fmaf(hr[i][1], wr2[m][1],
                               fmaf(hr[i][2], wr2[m][2], fmaf(hr[i][3], wr2[m][3], za[i][m]))));
        }
        #pragma unroll
        for (int i = 0; i < 4; ++i) {
            int r = rg2 * 4 + i;
            float t0 = fast_tanh(za[i][0]);
            float t1 = fast_tanh(za[i][1]);
            float t2 = fast_tanh(za[i][2]);
            float t3 = fast_tanh(za[i][3]);
            rsum[i] += (t0 + t1) + (t2 + t3);
            ushort4 tv4;
            tv4.x = __half_as_ushort(__float2half(t0));
            tv4.y = __half_as_ushort(__float2half(t1));
            tv4.z = __half_as_ushort(__float2half(t2));
            tv4.w = __half_as_ushort(__float2half(t3));
            *(ushort4*)&s_t[r * 516 + n0 + 4 * ng] = tv4;
        }
    }
    // reduce rowsums across the 32 ng lanes (within wave halves)
    #pragma unroll
    for (int i = 0; i < 4; ++i) {
        float s = rsum[i];
        #pragma unroll
        for (int msk = 1; msk < 32; msk <<= 1) s += __shfl_xor(s, msk, 64);
        if (ng == 0) {
            int r = rg2 * 4 + i;
            s_rs[r] = s_epsC[r] / s;   // eps*capSum / S
        }
    }
    __syncthreads();

    // ---- epilogue: out = x + t * (epsC/S) * capinv ----
    {
        const int rr  = t >> 7;
        const int col = (t & 127) * 4;
        #pragma unroll 4
        for (int q = 0; q < 16; ++q) {
            int r = q * 2 + rr;
            float rs = s_rs[r];
            float4 xv = *(const float4*)(x + (r0 + r) * 512 + col);
            ushort4 tv4 = *(const ushort4*)&s_t[r * 516 + col];
            float4 ci = *(const float4*)&s_ci[col];
            float4 o;
            o.x = fmaf(__half2float(__ushort_as_half(tv4.x)), rs * ci.x, xv.x);
            o.y = fmaf(__half2float(__ushort_as_half(tv4.y)), rs * ci.y, xv.y);
            o.z = fmaf(__half2float(__ushort_as_half(tv4.z)), rs * ci.z, xv.z);
            o.w = fmaf(__half2float(__ushort_as_half(tv4.w)), rs * ci.w, xv.w);
            *(float4*)(out + (r0 + r) * 512 + col) = o;
        }
    }
}

extern "C" void kernel_launch(void* const* d_in, const int* in_sizes, int n_in,
                              void* d_out, int out_size, void* d_ws, size_t ws_size,
                              hipStream_t stream) {
    const float* x     = (const float*)d_in[0];
    const float* xcons = (const float*)d_in[1];
    const float* cap   = (const float*)d_in[2];
    const float* W1    = (const float*)d_in[3];
    const float* b1    = (const float*)d_in[4];
    const float* W2    = (const float*)d_in[5];
    const float* b2    = (const float*)d_in[6];
    float* out         = (float*)d_out;
    float* ws          = (float*)d_ws;

    (void)in_sizes; (void)n_in; (void)out_size; (void)ws_size;

    prep_kernel<<<128, 256, 0, stream>>>(W1, W2, ws);

    hipFuncSetAttribute((const void*)fused_rgu,
                        hipFuncAttributeMaxDynamicSharedMemorySize, SMEM_BYTES);
    fused_rgu<<<NBLK, THREADS, SMEM_BYTES, stream>>>(
        x, xcons, cap, b1, b2, ws, out);
}